// Round 1
// baseline (323.652 us; speedup 1.0000x reference)
//
#include <hip/hip_runtime.h>
#include <math.h>

// HybridFrequencyEncoder: fused Haar DWT (1024x1024 -> 4x 512x512) + 8x8 DCT-II on LL.
// Input : x  (16,3,1024,1024) fp32
// Output: [LL_dct | LH | HL | HH] each (16,3,512,512) fp32, concatenated.
//
// One 256-thread block per 16-row x 128-col input tile:
//   - thread t: hr = t>>5 (half-res row 0..7), cp = t&31 (col-pair 0..31)
//   - loads float4 from even row + float4 from odd row (16B/lane, coalesced)
//   - computes 2 Haar outputs per subband in registers (no cross-lane)
//   - LH/HL/HH written directly (float2/lane, contiguous per wave)
//   - LL staged in LDS, separable 8x8 DCT (row pass -> T, col pass -> out)

#define H_IN   1024
#define W_IN   1024
#define H_HALF 512
#define W_HALF 512
#define NIMG   48                       // 16 * 3
#define NOUT   ((size_t)NIMG * H_HALF * W_HALF)   // 12,582,912 per subband

__global__ __launch_bounds__(256) void hfe_kernel(const float* __restrict__ x,
                                                  float* __restrict__ out) {
    __shared__ float Dm[8][8];     // DCT-II matrix
    __shared__ float M[8][65];     // LL tile (8 x 64, +1 pad)
    __shared__ float T[8][65];     // after row-pass

    const int t = threadIdx.x;

    // Build DCT matrix once per block (double precision to match numpy)
    if (t < 64) {
        const int k = t >> 3, n = t & 7;
        double v = (k == 0) ? 0.35355339059327376220
                            : 0.5 * cos(M_PI * (double)(k * (2 * n + 1)) / 16.0);
        Dm[k][n] = (float)v;
    }

    const int bid = blockIdx.x;
    const int bc  = bid >> 9;        // image index 0..47 (512 tiles/image)
    const int rem = bid & 511;
    const int ty  = rem >> 3;        // 0..63 : 16-row group
    const int tx  = rem & 7;         // 0..7  : 128-col group

    const int hr = t >> 5;           // 0..7  half-res row within tile
    const int cp = t & 31;           // 0..31 half-res col-pair within tile

    const int in_row = ty * 16 + hr * 2;
    const int in_col = tx * 128 + cp * 4;
    const float* base = x + (size_t)bc * (H_IN * W_IN);

    const float4 a = *(const float4*)(base + (size_t)in_row * W_IN + in_col);
    const float4 b = *(const float4*)(base + (size_t)(in_row + 1) * W_IN + in_col);

    // Haar: x00=even/even, x01=even/odd, x10=odd/even, x11=odd/odd
    const float ll0 = (a.x + a.y + b.x + b.y) * 0.5f;
    const float lh0 = (a.x + a.y - b.x - b.y) * 0.5f;
    const float hl0 = (a.x - a.y + b.x - b.y) * 0.5f;
    const float hh0 = (a.x - a.y - b.x + b.y) * 0.5f;
    const float ll1 = (a.z + a.w + b.z + b.w) * 0.5f;
    const float lh1 = (a.z + a.w - b.z - b.w) * 0.5f;
    const float hl1 = (a.z - a.w + b.z - b.w) * 0.5f;
    const float hh1 = (a.z - a.w - b.z + b.w) * 0.5f;

    const int h_row = ty * 8 + hr;
    const int h_col = tx * 64 + cp * 2;
    const size_t hidx = (size_t)bc * ((size_t)H_HALF * W_HALF)
                      + (size_t)h_row * W_HALF + h_col;

    *(float2*)(out + NOUT     + hidx) = make_float2(lh0, lh1);
    *(float2*)(out + 2 * NOUT + hidx) = make_float2(hl0, hl1);
    *(float2*)(out + 3 * NOUT + hidx) = make_float2(hh0, hh1);

    M[hr][cp * 2]     = ll0;
    M[hr][cp * 2 + 1] = ll1;

    __syncthreads();

    // Row pass: T[m][b*8+l] = sum_n M[m][b*8+n] * D[l][n]
    {
        const int blk = cp >> 2;           // 8x8 block index 0..7 (both cols same block)
        const int l0  = (cp * 2) & 7;
        const float* mrow = &M[hr][blk * 8];
        float t0 = 0.f, t1 = 0.f;
#pragma unroll
        for (int n = 0; n < 8; ++n) {
            const float mv = mrow[n];
            t0 += mv * Dm[l0][n];
            t1 += mv * Dm[l0 + 1][n];
        }
        T[hr][cp * 2]     = t0;
        T[hr][cp * 2 + 1] = t1;
    }

    __syncthreads();

    // Col pass: out[k][col] = sum_m D[k][m] * T[m][col]
    {
        float o0 = 0.f, o1 = 0.f;
#pragma unroll
        for (int m = 0; m < 8; ++m) {
            const float dk = Dm[hr][m];
            o0 += dk * T[m][cp * 2];
            o1 += dk * T[m][cp * 2 + 1];
        }
        *(float2*)(out + hidx) = make_float2(o0, o1);
    }
}

extern "C" void kernel_launch(void* const* d_in, const int* in_sizes, int n_in,
                              void* d_out, int out_size, void* d_ws, size_t ws_size,
                              hipStream_t stream) {
    const float* x = (const float*)d_in[0];
    float* out = (float*)d_out;
    // 48 images * (1024/16 row-tiles) * (1024/128 col-tiles) = 48*64*8 = 24576 blocks
    hfe_kernel<<<dim3(NIMG * 64 * 8), dim3(256), 0, stream>>>(x, out);
}